// Round 25
// baseline (75.205 us; speedup 1.0000x reference)
//
#include <hip/hip_runtime.h>
#include <math.h>

#define NTOK 16384
#define DDIM 2048
#define NEXP 64
#define MT   32                  // tokens per block (2 quads of 16)
#define KCH  32                  // k per chunk = 1 MFMA k-step
#define NCH  (DDIM / KCH)        // 64

// ws layout: [0..128] acc (f counts / P sums / z). floats.
// [WF_OFF ...] W fragments: bf16[3 levels][4 groups][64 ksteps][64 lanes][8]
#define ACC_N  129
#define WF_OFF 256
#define VSTRIDE ((size_t)4 * 64 * 64 * 8)   // ushorts per level

typedef __attribute__((ext_vector_type(8))) short short8_t;
typedef __attribute__((ext_vector_type(4))) short short4_t;
typedef __attribute__((ext_vector_type(4))) float f32x4;

// exact RNE fp32->bf16 (bit trick), and back
__device__ __forceinline__ unsigned short f2bf(float f) {
    unsigned int u = __float_as_uint(f);
    u += 0x7fffu + ((u >> 16) & 1u);
    return (unsigned short)(u >> 16);
}
__device__ __forceinline__ float bf2f(unsigned short s) {
    return __uint_as_float(((unsigned int)s) << 16);
}

__device__ __forceinline__ void gload16(const void* g, const void* lds) {
    __builtin_amdgcn_global_load_lds(
        (const __attribute__((address_space(1))) unsigned int*)g,
        (__attribute__((address_space(3))) unsigned int*)lds, 16, 0, 0);
}

// prep: zero acc; split W into 3 exact bf16 levels in MFMA B-fragment order:
// wf[v][g][ks][lane][j] = level_v of W[ks*32+(lane>>4)*8+j][g*16+(lane&15)]
__global__ __launch_bounds__(256) void prep(
    const float* __restrict__ W, float* __restrict__ ws)
{
    const int i = blockIdx.x * 256 + threadIdx.x;   // 0..131071
    if (blockIdx.x == 0 && threadIdx.x < ACC_N) ws[threadIdx.x] = 0.0f;
    const int k = i >> 6, e = i & 63;
    const float v = W[i];
    unsigned short h = f2bf(v);
    float r1 = v - bf2f(h);                 // exact (Sterbenz)
    unsigned short m = f2bf(r1);
    unsigned short l = f2bf(r1 - bf2f(m));  // exact
    unsigned short* wf = (unsigned short*)(ws + WF_OFF);
    const int g = e >> 4, ks = k >> 5;
    const int lane = (((k >> 3) & 3) << 4) | (e & 15);
    const int j = k & 7;
    const size_t base = ((((size_t)g * 64) + ks) * 64 + lane) * 8 + j;
    wf[base] = h;
    wf[VSTRIDE + base] = m;
    wf[2 * VSTRIDE + base] = l;
}

// Fused MFMA gate, r25: B-fragments staged into LDS via global_load_lds
// one chunk ahead (drained by the loop barrier -> B-latency leaves the
// per-wave chain; r18-r24 evidence: latency-bound, all throughput
// resources <=20%, compiler refuses to hoist B loads -- VGPR 44-60).
//
// Bank math (all at the 8-dword/bank b128 service optimum, no swizzle):
//  A [32][32] bf16 linear: row stride 64B = half a bank wrap, so the 16
//  rows of a frag-read alternate bank halves; (l&15)*16+(l>>4)*4+d mod 32
//  covers each bank exactly 8x. conv b64 writes: 4 dwords/bank, even.
//  B lane-linear: l*4+d mod 32 -> 8/bank.
__global__ __launch_bounds__(256, 3) void gate_fused(
    const float* __restrict__ x, const unsigned short* __restrict__ wf,
    const float* __restrict__ bias, float* __restrict__ out,
    float* __restrict__ acc_g)
{
    __shared__ __align__(16) unsigned short xa[2][3][MT * KCH];   // 12 KB
    __shared__ __align__(16) unsigned short bl_[2][3][256 * 8];   // 24 KB
    __shared__ float logits[MT][68];
    __shared__ int   f_loc[NEXP];
    __shared__ float p_loc[NEXP];
    __shared__ float z_loc;

    const int tid  = threadIdx.x;
    const int tok0 = blockIdx.x * MT;
    const int lane = tid & 63;
    const int g    = __builtin_amdgcn_readfirstlane(tid >> 6);  // expert group

    if (tid < NEXP) { f_loc[tid] = 0; p_loc[tid] = 0.0f; }
    if (tid == 0) z_loc = 0.0f;

    // x staging: thread owns row = tid>>3 (0..31), 4 floats at col cg*4
    const int srow = tid >> 3;
    const int cg   = tid & 7;
    const float* xs = x + (size_t)(tok0 + srow) * DDIM + cg * 4;
    const int abase_w = srow * KCH + cg * 4;       // ushort store base

    // B DMA source: thread tid covers (g2=tid>>6, lane2=tid&63) of kstep ks
    const int g2 = tid >> 6, lane2 = tid & 63;
    const unsigned short* wsrc =
        wf + (((size_t)g2 * 64) * 64 + lane2) * 8;   // + ks*64*8 per chunk

    // A-fragment addressing: lane l, quad q -> row 16q+(l&15), granule akq
    const int arow16 = lane & 15;
    const int akq    = lane >> 4;

    f32x4 acc[2][3];
    #pragma unroll
    for (int q = 0; q < 2; ++q)
        #pragma unroll
        for (int ch = 0; ch < 3; ++ch)
            acc[q][ch] = (f32x4){0.f, 0.f, 0.f, 0.f};

    // ---- prologue: stage chunk 0 (A conv + B DMA); preload x chunk 1 ----
    {
        float4 a0 = *(const float4*)xs;
        float xv[4];
        *(float4*)xv = a0;
        unsigned short th[4], tm[4], tl[4];
        #pragma unroll
        for (int i = 0; i < 4; ++i) {
            float f = xv[i];
            th[i] = f2bf(f);
            float r = f - bf2f(th[i]);
            tm[i] = f2bf(r);
            tl[i] = f2bf(r - bf2f(tm[i]));
        }
        *(short4_t*)&xa[0][0][abase_w] = *(short4_t*)&th[0];
        *(short4_t*)&xa[0][1][abase_w] = *(short4_t*)&tm[0];
        *(short4_t*)&xa[0][2][abase_w] = *(short4_t*)&tl[0];
        #pragma unroll
        for (int v = 0; v < 3; ++v)
            gload16(wsrc + (size_t)v * VSTRIDE, &bl_[0][v][tid * 8]);
    }
    float4 pv = *(const float4*)(xs + KCH);

    #pragma unroll 1
    for (int c = 0; c < NCH; ++c) {
        __syncthreads();   // chunk c fully staged (lgkm + vmcnt drained)
        const int cb = c & 1, nb = cb ^ 1;

        if (c + 1 < NCH) {
            // issue B(c+1) DMA FIRST: a full conv+MFMA phase to land
            const unsigned short* wsn = wsrc + (size_t)(c + 1) * 64 * 8;
            #pragma unroll
            for (int v = 0; v < 3; ++v)
                gload16(wsn + (size_t)v * VSTRIDE, &bl_[nb][v][tid * 8]);
            // conv A(c+1) from preloaded registers
            float xv[4];
            *(float4*)xv = pv;
            unsigned short th[4], tm[4], tl[4];
            #pragma unroll
            for (int i = 0; i < 4; ++i) {
                float f = xv[i];
                th[i] = f2bf(f);
                float r = f - bf2f(th[i]);      // exact
                tm[i] = f2bf(r);
                tl[i] = f2bf(r - bf2f(tm[i]));  // exact
            }
            *(short4_t*)&xa[nb][0][abase_w] = *(short4_t*)&th[0];
            *(short4_t*)&xa[nb][1][abase_w] = *(short4_t*)&tm[0];
            *(short4_t*)&xa[nb][2][abase_w] = *(short4_t*)&tl[0];
            if (c + 2 < NCH)
                pv = *(const float4*)(xs + (c + 2) * KCH);
        }

        // MFMA: 1 k-step x (1 B-set x 2 quads x 6 products), all from LDS
        __builtin_amdgcn_s_setprio(1);
        const int bb_ = (g * 64 + lane) * 8;
        short8_t bh = *(const short8_t*)&bl_[cb][0][bb_];
        short8_t bm = *(const short8_t*)&bl_[cb][1][bb_];
        short8_t blv = *(const short8_t*)&bl_[cb][2][bb_];
        #pragma unroll
        for (int q = 0; q < 2; ++q) {
            const int ab = (16 * q + arow16) * KCH + akq * 8;
            short8_t ah = *(const short8_t*)&xa[cb][0][ab];
            short8_t am = *(const short8_t*)&xa[cb][1][ab];
            short8_t al = *(const short8_t*)&xa[cb][2][ab];
            acc[q][0] = __builtin_amdgcn_mfma_f32_16x16x32_bf16(ah, bh,  acc[q][0], 0, 0, 0);
            acc[q][1] = __builtin_amdgcn_mfma_f32_16x16x32_bf16(ah, bm,  acc[q][1], 0, 0, 0);
            acc[q][2] = __builtin_amdgcn_mfma_f32_16x16x32_bf16(am, bm,  acc[q][2], 0, 0, 0);
            acc[q][0] = __builtin_amdgcn_mfma_f32_16x16x32_bf16(ah, blv, acc[q][0], 0, 0, 0);
            acc[q][1] = __builtin_amdgcn_mfma_f32_16x16x32_bf16(am, bh,  acc[q][1], 0, 0, 0);
            acc[q][2] = __builtin_amdgcn_mfma_f32_16x16x32_bf16(al, bh,  acc[q][2], 0, 0, 0);
        }
        __builtin_amdgcn_s_setprio(0);
    }

    // C layout (m89): col = lane&15, row(within quad) = (lane>>4)*4 + reg
    #pragma unroll
    for (int q = 0; q < 2; ++q)
        #pragma unroll
        for (int r = 0; r < 4; ++r)
            logits[16 * q + akq * 4 + r][g * 16 + arow16] =
                (acc[q][0][r] + acc[q][1][r]) + acc[q][2][r];
    __syncthreads();

    // ---- fused epilogue (r24-verified logic), 2 x 16-token groups ----
    const int tx  = tid & 15;         // expert group of 4
    const int tgs = tid >> 4;         // token slot 0..15
    const int e0  = tx * 4;

    float bbv[4];
    *(float4*)bbv = *(const float4*)&bias[e0];

    float pacc[4] = {0.f, 0.f, 0.f, 0.f};
    float zacc = 0.0f;

    #pragma unroll
    for (int it = 0; it < 2; ++it) {
        const int t  = it * 16 + tgs;
        const int gt = tok0 + t;

        float l[4];
        {
            float4 lv = *(const float4*)&logits[t][e0];
            l[0] = lv.x + bbv[0]; l[1] = lv.y + bbv[1];
            l[2] = lv.z + bbv[2]; l[3] = lv.w + bbv[3];
        }

        // local top-2 (stable: ascending e, strict >)
        float v1 = l[0], v2 = -INFINITY;
        int   i1 = e0,   i2 = 0x7fffffff;
        #pragma unroll
        for (int j = 1; j < 4; ++j) {
            float v = l[j]; int e = e0 + j;
            if (v > v1)      { v2 = v1; i2 = i1; v1 = v; i1 = e; }
            else if (v > v2) { v2 = v;  i2 = e; }
        }
        // merge across the 16 lanes of this token (value desc, idx asc)
        #pragma unroll
        for (int off = 1; off < 16; off <<= 1) {
            float o1 = __shfl_xor(v1, off, 16); int oi1 = __shfl_xor(i1, off, 16);
            float o2 = __shfl_xor(v2, off, 16); int oi2 = __shfl_xor(i2, off, 16);
            if (o1 > v1 || (o1 == v1 && oi1 < i1)) {
                float cs = v1; int ci = i1;
                v1 = o1; i1 = oi1;
                if (cs > o2 || (cs == o2 && ci < oi2)) { v2 = cs; i2 = ci;  }
                else                                   { v2 = o2; i2 = oi2; }
            } else {
                if (o1 > v2 || (o1 == v2 && oi1 < i2)) { v2 = o1; i2 = oi1; }
            }
        }
        const float mx = v1;

        float sden[4], dsum = 0.0f;
        #pragma unroll
        for (int j = 0; j < 4; ++j) { sden[j] = __expf(l[j] - mx); dsum += sden[j]; }
        #pragma unroll
        for (int off = 1; off < 16; off <<= 1) dsum += __shfl_xor(dsum, off, 16);
        const float inv = 1.0f / dsum;

        float zsum = 0.0f;
        #pragma unroll
        for (int j = 0; j < 4; ++j) {
            float pj = sden[j] * inv;
            pacc[j] += pj;
            zsum += __expf(pj);
        }
        #pragma unroll
        for (int off = 1; off < 16; off <<= 1) zsum += __shfl_xor(zsum, off, 16);

        if (tx == 0) {
            const float s2 = __expf(v2 - mx);      // s1 == 1
            const float ci = 1.0f / (1.0f + s2);
            out[2 * gt]     = (float)i1;
            out[2 * gt + 1] = (float)i2;
            out[2 * NTOK + 2 * gt]     = ci;
            out[2 * NTOK + 2 * gt + 1] = s2 * ci;
            atomicAdd(&f_loc[i1], 1);
            float lse = __logf(zsum);
            zacc += lse * lse;
        }
    }

    // z: wave-reduce (only tx==0 lanes nonzero), one LDS atomic per wave
    #pragma unroll
    for (int off = 1; off < 64; off <<= 1) zacc += __shfl_xor(zacc, off);
    if ((tid & 63) == 0) atomicAdd(&z_loc, zacc);

    // P: fold token-groups within wave, then LDS
    #pragma unroll
    for (int j = 0; j < 4; ++j) {
        pacc[j] += __shfl_xor(pacc[j], 16);
        pacc[j] += __shfl_xor(pacc[j], 32);
    }
    if ((tid & 63) < 16) {
        #pragma unroll
        for (int j = 0; j < 4; ++j) atomicAdd(&p_loc[e0 + j], pacc[j]);
    }

    __syncthreads();
    if (tid < NEXP) {
        atomicAdd(&acc_g[64 + tid], p_loc[tid]);
        if (f_loc[tid]) atomicAdd(&acc_g[tid], (float)f_loc[tid]);
    }
    if (tid == 0) atomicAdd(&acc_g[128], z_loc);
}

__global__ void gate_finalize(const float* __restrict__ acc, float* __restrict__ out) {
    int e = threadIdx.x;  // 64 threads
    float v = acc[e] * acc[64 + e];
    #pragma unroll
    for (int off = 32; off > 0; off >>= 1) v += __shfl_down(v, off);
    if (e == 0) {
        const float NT = (float)NTOK;
        out[2 * NTOK * 2]     = 0.01f * (v / (float)NEXP) / (NT * NT);
        out[2 * NTOK * 2 + 1] = 0.1f * acc[128] / NT;
    }
}

extern "C" void kernel_launch(void* const* d_in, const int* in_sizes, int n_in,
                              void* d_out, int out_size, void* d_ws, size_t ws_size,
                              hipStream_t stream) {
    const float* x    = (const float*)d_in[0];
    const float* W    = (const float*)d_in[1];
    const float* bias = (const float*)d_in[2];
    float* out = (float*)d_out;
    float* ws  = (float*)d_ws;
    const unsigned short* wfrag = (const unsigned short*)(ws + WF_OFF);

    prep<<<(DDIM * NEXP) / 256, 256, 0, stream>>>(W, ws);
    gate_fused<<<NTOK / MT, 256, 0, stream>>>(x, wfrag, bias, out, ws);
    gate_finalize<<<1, 64, 0, stream>>>(ws, out);
}